// Round 6
// baseline (231.926 us; speedup 1.0000x reference)
//
#include <hip/hip_runtime.h>
#include <hip/hip_fp16.h>

// AxialAttention on MI355X (gfx950).
// x: [8,128,128,128] fp32, attend along H. Problem = (n0,h,w): S=128, d=16.
// K1 (attn): fully-MFMA. Block = (n0,h,xcd) = 1024 thr / 16 waves, owns the
//   16 consecutive w of one XCD stripe (1 problem per wave). x staging is
//   perfectly coalesced: lane quads q=0..3 cover a full 64B line (float4 at
//   w0+q*4); every x line fetched once, fully consumed by one instruction.
//   LDS x-tile f16 = 80KB -> exactly 2 blocks/CU (32 waves/CU), grid 512
//   all-resident. Fragment chain (D==A/B layout identity of 16x16x16 MFMA):
//     Q^T = mfma(Wq, y^T) (scaled by 1/sqrt(128)*log2e), K^T = mfma(Wk, y^T),
//     V = mfma(y, Wv^T), P^T = exp2(mfma(K, Q)), O = mfma(P, V) (2 chains).
//   AO written bf16 [b=(n0,w)][s][c]. Wo->bf16 prep folded in (32 elem/block).
// K2 (proj): block=(n0,s,w-half). Wo A-frags preloaded to regs, AO half-tile
//   (64w x 128c bf16) staged to LDS, 4 waves x (32e x 64w) 16x16x32 bf16 MFMA.

typedef __attribute__((ext_vector_type(4))) float f32x4;
typedef __attribute__((ext_vector_type(4))) _Float16 f16x4;
typedef __attribute__((ext_vector_type(8))) short bf16x8;

__device__ __forceinline__ unsigned int bf16_rne(float x) {
    unsigned int u = __float_as_uint(x);
    return (u + 0x7fffu + ((u >> 16) & 1u)) >> 16;
}
__device__ __forceinline__ unsigned int pack_half2(float a, float b) {
    __half2 h = __floats2half2_rn(a, b);
    return *reinterpret_cast<unsigned int*>(&h);
}

__global__ __launch_bounds__(1024, 8) void axattn_attn(
    const float* __restrict__ x,
    const float* __restrict__ Wq,
    const float* __restrict__ Wk,
    const float* __restrict__ Wv,
    const float* __restrict__ Wo,
    unsigned short* __restrict__ Wob,
    unsigned short* __restrict__ AO)   // bf16 [(n0*128+w)][s][c]
{
    // bb = (n0*8 + h)*8 + xcd ; w0 = xcd*16 ; wave wvi: w = w0 + wvi
    int bb  = blockIdx.x;
    int xcd = bb & 7;
    int nh  = bb >> 3;         // n0*8 + h
    int n0  = nh >> 3;
    int h   = nh & 7;
    int tid = threadIdx.x;
    int wvi = tid >> 6;        // wave 0..15 -> own problem (w)
    int l   = tid & 63;
    int lr  = l & 15;          // fragment row/col index
    int lg  = l >> 4;          // fragment k-group
    int w0  = xcd * 16;
    int w   = w0 + wvi;

    // folded prep: Wo fp32 -> bf16 (512 blocks x 32 = 16384 elements)
    if (tid < 32) {
        int i = bb * 32 + tid;
        Wob[i] = (unsigned short)bf16_rne(Wo[i]);
    }

    // x-tile as f16: [w-local 0..15][row][c2] ; row stride 10 u32 (40B)
    __shared__ unsigned int xs[16 * 1280];   // 80 KB

    // Staging: tid -> (q = w-quad 0..3, row, c2b); 4 c2 per thread.
    // Per wave-instr: lane quads cover 64B contiguous (full line), 16 rows.
    {
        int q   = tid & 3;
        int row = (tid >> 2) & 127;
        int c2b = tid >> 9;    // 0/1
        const float* gp0 = x + ((size_t)(n0 * 128 + h * 16) * 128 + row) * 128 + w0 + q * 4;
        #pragma unroll
        for (int it = 0; it < 4; ++it) {
            int c2 = it * 2 + c2b;
            const float* gp = gp0 + (size_t)(2 * c2) * 16384;
            float4 va = *(const float4*)gp;            // c = 2*c2
            float4 vb = *(const float4*)(gp + 16384);  // c = 2*c2+1
            unsigned int* dp = xs + (q * 4) * 1280 + row * 10 + c2;
            dp[0]    = pack_half2(va.x, vb.x);
            dp[1280] = pack_half2(va.y, vb.y);
            dp[2560] = pack_half2(va.z, vb.z);
            dp[3840] = pack_half2(va.w, vb.w);
        }
    }

    const float qsc = 0.088388347648318447f * 1.4426950408889634f; // 1/sqrt(128)*log2e
    const f32x4 zf = {0.f, 0.f, 0.f, 0.f};

    // Weight fragments: lane reads W[lr][lg*4 .. +3] (overlaps staging).
    float4 wqf = *(const float4*)(Wq + lr * 16 + lg * 4);
    float4 wkf = *(const float4*)(Wk + lr * 16 + lg * 4);
    float4 wvf = *(const float4*)(Wv + lr * 16 + lg * 4);
    f16x4 fq = {(_Float16)wqf.x, (_Float16)wqf.y, (_Float16)wqf.z, (_Float16)wqf.w};
    f16x4 fk = {(_Float16)wkf.x, (_Float16)wkf.y, (_Float16)wkf.z, (_Float16)wkf.w};
    f16x4 fv = {(_Float16)wvf.x, (_Float16)wvf.y, (_Float16)wvf.z, (_Float16)wvf.w};

    __syncthreads();

    // y fragments from LDS: yf[rt][j] = y[rt*16+lr][lg*4+j]
    const char* yb = (const char*)xs + wvi * 5120 + lr * 40 + lg * 8;
    f16x4 yf[8];
    #pragma unroll
    for (int rt = 0; rt < 8; ++rt)
        yf[rt] = *(const f16x4*)(yb + rt * 640);   // 16 rows * 40B

    // Projections: per 16-row tile t.
    f16x4 qb[8], ka[8], vb[8];
    #pragma unroll
    for (int t = 0; t < 8; ++t) {
        f32x4 qt = __builtin_amdgcn_mfma_f32_16x16x16f16(fq, yf[t], zf, 0, 0, 0);
        f32x4 kt = __builtin_amdgcn_mfma_f32_16x16x16f16(fk, yf[t], zf, 0, 0, 0);
        f32x4 vt = __builtin_amdgcn_mfma_f32_16x16x16f16(yf[t], fv, zf, 0, 0, 0);
        qb[t] = (f16x4){(_Float16)(qt[0] * qsc), (_Float16)(qt[1] * qsc),
                        (_Float16)(qt[2] * qsc), (_Float16)(qt[3] * qsc)};
        ka[t] = (f16x4){(_Float16)kt[0], (_Float16)kt[1], (_Float16)kt[2], (_Float16)kt[3]};
        vb[t] = (f16x4){(_Float16)vt[0], (_Float16)vt[1], (_Float16)vt[2], (_Float16)vt[3]};
    }

    // AO base for this lane: row q = qt*16 + lg*4 + r, col c = h*16 + lr.
    unsigned short* aob = AO + ((size_t)(n0 * 128 + w) * 128 + lg * 4) * 128 + h * 16 + lr;

    #pragma unroll
    for (int qt = 0; qt < 8; ++qt) {
        f32x4 s[8];
        #pragma unroll
        for (int kt = 0; kt < 8; ++kt)
            s[kt] = __builtin_amdgcn_mfma_f32_16x16x16f16(ka[kt], qb[qt], zf, 0, 0, 0);
        float sum = 0.f;
        f16x4 pa[8];
        #pragma unroll
        for (int kt = 0; kt < 8; ++kt) {
            float p0 = __builtin_amdgcn_exp2f(s[kt][0]);
            float p1 = __builtin_amdgcn_exp2f(s[kt][1]);
            float p2 = __builtin_amdgcn_exp2f(s[kt][2]);
            float p3 = __builtin_amdgcn_exp2f(s[kt][3]);
            sum += (p0 + p1) + (p2 + p3);
            pa[kt] = (f16x4){(_Float16)p0, (_Float16)p1, (_Float16)p2, (_Float16)p3};
        }
        sum += __shfl_xor(sum, 16);
        sum += __shfl_xor(sum, 32);
        // PV as two independent 4-deep chains (halves serial MFMA latency)
        f32x4 oA = zf, oB = zf;
        #pragma unroll
        for (int kt = 0; kt < 4; ++kt) {
            oA = __builtin_amdgcn_mfma_f32_16x16x16f16(pa[kt],     vb[kt],     oA, 0, 0, 0);
            oB = __builtin_amdgcn_mfma_f32_16x16x16f16(pa[kt + 4], vb[kt + 4], oB, 0, 0, 0);
        }
        f32x4 o = oA + oB;
        float rl = 1.f / sum;      // valid for q-column lr
        #pragma unroll
        for (int r = 0; r < 4; ++r) {
            float rs = __shfl(rl, lg * 4 + r);   // 1/sum for q-row lg*4+r
            aob[((size_t)qt * 16 + r) * 128] = (unsigned short)bf16_rne(o[r] * rs);
        }
    }
}

// MFMA out-proj. Block = (n0, s, w-half); Wo A-frags preloaded to regs,
// AO half-tile staged to LDS; 4 waves, wave wv: e-tile [wv*32,+32) x 64 w.
__global__ __launch_bounds__(256) void axattn_proj(
    const unsigned short* __restrict__ AOb,
    const unsigned short* __restrict__ Wob,
    const float* __restrict__ bo,
    float* __restrict__ out)
{
    int bb  = blockIdx.x;
    int wh  = bb & 1;
    int s   = (bb >> 1) & 127;
    int n0  = bb >> 8;
    int tid = threadIdx.x;
    int wv  = tid >> 6;
    int l   = tid & 63;
    int lr  = l & 15;
    int lg  = l >> 4;
    int lk  = lg * 8;
    int eb  = wv * 32;

    // AO half-tile [w-row 0..63][c 0..127] bf16, row stride 272B (256 + 16 pad)
    __shared__ char as_[64 * 272];

    // A-frags first: global loads overlap the LDS staging below.
    const unsigned short* wp_ = Wob + (size_t)(eb + lr) * 128 + lk;
    bf16x8 a0[4], a1[4];
    #pragma unroll
    for (int ct = 0; ct < 4; ++ct) {
        a0[ct] = *(const bf16x8*)(wp_ + ct * 32);
        a1[ct] = *(const bf16x8*)(wp_ + 16 * 128 + ct * 32);
    }

    #pragma unroll
    for (int it = 0; it < 4; ++it) {
        int flat = it * 256 + tid;     // 0..1023
        int row  = flat >> 4;          // 0..63
        int seg  = flat & 15;
        const uint4* src = (const uint4*)(AOb
            + ((size_t)(n0 * 128 + wh * 64 + row) * 128 + s) * 128) + seg;
        *(uint4*)(as_ + row * 272 + seg * 16) = *src;
    }
    __syncthreads();

    f32x4 acc[2][4];
    #pragma unroll
    for (int mi = 0; mi < 2; ++mi)
        #pragma unroll
        for (int ni = 0; ni < 4; ++ni)
            acc[mi][ni] = (f32x4){0.f, 0.f, 0.f, 0.f};

    #pragma unroll
    for (int ct = 0; ct < 4; ++ct) {             // k = c tile of 32
        #pragma unroll
        for (int ni = 0; ni < 4; ++ni) {
            bf16x8 b = *(const bf16x8*)(as_ + (ni * 16 + lr) * 272 + (lk + ct * 32) * 2);
            acc[0][ni] = __builtin_amdgcn_mfma_f32_16x16x32_bf16(a0[ct], b, acc[0][ni], 0, 0, 0);
            acc[1][ni] = __builtin_amdgcn_mfma_f32_16x16x32_bf16(a1[ct], b, acc[1][ni], 0, 0, 0);
        }
    }

    int r4 = lg * 4;
    #pragma unroll
    for (int mi = 0; mi < 2; ++mi) {
        #pragma unroll
        for (int r = 0; r < 4; ++r) {
            int e = eb + mi * 16 + r4 + r;
            float bv = bo[e];
            float* orow = out + ((size_t)(n0 * 128 + e) * 128 + s) * 128 + wh * 64 + lr;
            #pragma unroll
            for (int ni = 0; ni < 4; ++ni)
                orow[ni * 16] = acc[mi][ni][r] + bv;
        }
    }
}

extern "C" void kernel_launch(void* const* d_in, const int* in_sizes, int n_in,
                              void* d_out, int out_size, void* d_ws, size_t ws_size,
                              hipStream_t stream) {
    const float* x  = (const float*)d_in[0];
    const float* Wq = (const float*)d_in[1];
    const float* Wk = (const float*)d_in[2];
    const float* Wv = (const float*)d_in[3];
    const float* Wo = (const float*)d_in[4];
    const float* bo = (const float*)d_in[5];
    float* out = (float*)d_out;

    unsigned short* AOb = (unsigned short*)d_ws;                        // 32 MiB bf16
    unsigned short* Wob = (unsigned short*)((char*)d_ws + (32u << 20)); // 32 KiB bf16

    axattn_attn<<<512, 1024, 0, stream>>>(x, Wq, Wk, Wv, Wo, Wob, AOb);
    axattn_proj<<<2048, 256, 0, stream>>>(AOb, Wob, bo, out);
}

// Round 7
// 157.490 us; speedup vs baseline: 1.4726x; 1.4726x over previous
//
#include <hip/hip_runtime.h>
#include <hip/hip_fp16.h>

// AxialAttention on MI355X (gfx950).
// x: [8,128,128,128] fp32, attend along H. Problem = (n0,h,w): S=128, d=16.
// K1 (attn): fully-MFMA. Block = (n0,h,xcd) = 1024 thr / 16 waves, owns the
//   16 consecutive w of one XCD stripe (1 problem per wave). x staging is
//   perfectly coalesced: lane quads q=0..3 cover a full 64B line (float4 at
//   w0+q*4); every x line fetched once, fully consumed by one instruction.
//   LDS x-tile f16 = 80KB -> 2 blocks/CU (32 waves/CU), grid 512 all-resident.
//   __launch_bounds__(1024, 4): VGPR cap 128 (NOT 8 -> cap 64 -> round-6's
//   spill disaster: VGPR=32, +237MB scratch traffic). Body needs ~56 VGPR.
//   Fragment chain (D==A/B layout identity of 16x16x16 MFMA):
//     Q^T = mfma(Wq, y^T) (scaled by 1/sqrt(128)*log2e), K^T = mfma(Wk, y^T),
//     V = mfma(y, Wv^T), P^T = exp2(mfma(K, Q)), O = mfma(P, V) (2 chains).
//   AO written bf16 [b=(n0,w)][s][c]. Wo->bf16 prep folded in (32 elem/block).
// K2 (proj): block=(n0,s,w-half). Wo A-frags preloaded to regs, AO half-tile
//   (64w x 128c bf16) staged to LDS, 4 waves x (32e x 64w) 16x16x32 bf16 MFMA.

typedef __attribute__((ext_vector_type(4))) float f32x4;
typedef __attribute__((ext_vector_type(4))) _Float16 f16x4;
typedef __attribute__((ext_vector_type(8))) short bf16x8;

__device__ __forceinline__ unsigned int bf16_rne(float x) {
    unsigned int u = __float_as_uint(x);
    return (u + 0x7fffu + ((u >> 16) & 1u)) >> 16;
}
__device__ __forceinline__ unsigned int pack_half2(float a, float b) {
    __half2 h = __floats2half2_rn(a, b);
    return *reinterpret_cast<unsigned int*>(&h);
}

__global__ __launch_bounds__(1024, 4) void axattn_attn(
    const float* __restrict__ x,
    const float* __restrict__ Wq,
    const float* __restrict__ Wk,
    const float* __restrict__ Wv,
    const float* __restrict__ Wo,
    unsigned short* __restrict__ Wob,
    unsigned short* __restrict__ AO)   // bf16 [(n0*128+w)][s][c]
{
    // bb = (n0*8 + h)*8 + xcd ; w0 = xcd*16 ; wave wvi: w = w0 + wvi
    int bb  = blockIdx.x;
    int xcd = bb & 7;
    int nh  = bb >> 3;         // n0*8 + h
    int n0  = nh >> 3;
    int h   = nh & 7;
    int tid = threadIdx.x;
    int wvi = tid >> 6;        // wave 0..15 -> own problem (w)
    int l   = tid & 63;
    int lr  = l & 15;          // fragment row/col index
    int lg  = l >> 4;          // fragment k-group
    int w0  = xcd * 16;
    int w   = w0 + wvi;

    // folded prep: Wo fp32 -> bf16 (512 blocks x 32 = 16384 elements)
    if (tid < 32) {
        int i = bb * 32 + tid;
        Wob[i] = (unsigned short)bf16_rne(Wo[i]);
    }

    // x-tile as f16: [w-local 0..15][row][c2] ; row stride 10 u32 (40B)
    __shared__ unsigned int xs[16 * 1280];   // 80 KB

    // Staging: tid -> (q = w-quad 0..3, row, c2b); 4 c2 per thread.
    // Per wave-instr: lane quads cover 64B contiguous (full line), 16 rows.
    {
        int q   = tid & 3;
        int row = (tid >> 2) & 127;
        int c2b = tid >> 9;    // 0/1
        const float* gp0 = x + ((size_t)(n0 * 128 + h * 16) * 128 + row) * 128 + w0 + q * 4;
        #pragma unroll
        for (int it = 0; it < 4; ++it) {
            int c2 = it * 2 + c2b;
            const float* gp = gp0 + (size_t)(2 * c2) * 16384;
            float4 va = *(const float4*)gp;            // c = 2*c2
            float4 vb = *(const float4*)(gp + 16384);  // c = 2*c2+1
            unsigned int* dp = xs + (q * 4) * 1280 + row * 10 + c2;
            dp[0]    = pack_half2(va.x, vb.x);
            dp[1280] = pack_half2(va.y, vb.y);
            dp[2560] = pack_half2(va.z, vb.z);
            dp[3840] = pack_half2(va.w, vb.w);
        }
    }

    const float qsc = 0.088388347648318447f * 1.4426950408889634f; // 1/sqrt(128)*log2e
    const f32x4 zf = {0.f, 0.f, 0.f, 0.f};

    // Weight fragments: lane reads W[lr][lg*4 .. +3] (overlaps staging).
    float4 wqf = *(const float4*)(Wq + lr * 16 + lg * 4);
    float4 wkf = *(const float4*)(Wk + lr * 16 + lg * 4);
    float4 wvf = *(const float4*)(Wv + lr * 16 + lg * 4);
    f16x4 fq = {(_Float16)wqf.x, (_Float16)wqf.y, (_Float16)wqf.z, (_Float16)wqf.w};
    f16x4 fk = {(_Float16)wkf.x, (_Float16)wkf.y, (_Float16)wkf.z, (_Float16)wkf.w};
    f16x4 fv = {(_Float16)wvf.x, (_Float16)wvf.y, (_Float16)wvf.z, (_Float16)wvf.w};

    __syncthreads();

    // y fragments from LDS: yf[rt][j] = y[rt*16+lr][lg*4+j]
    const char* yb = (const char*)xs + wvi * 5120 + lr * 40 + lg * 8;
    f16x4 yf[8];
    #pragma unroll
    for (int rt = 0; rt < 8; ++rt)
        yf[rt] = *(const f16x4*)(yb + rt * 640);   // 16 rows * 40B

    // Projections: per 16-row tile t.
    f16x4 qb[8], ka[8], vb[8];
    #pragma unroll
    for (int t = 0; t < 8; ++t) {
        f32x4 qt = __builtin_amdgcn_mfma_f32_16x16x16f16(fq, yf[t], zf, 0, 0, 0);
        f32x4 kt = __builtin_amdgcn_mfma_f32_16x16x16f16(fk, yf[t], zf, 0, 0, 0);
        f32x4 vt = __builtin_amdgcn_mfma_f32_16x16x16f16(yf[t], fv, zf, 0, 0, 0);
        qb[t] = (f16x4){(_Float16)(qt[0] * qsc), (_Float16)(qt[1] * qsc),
                        (_Float16)(qt[2] * qsc), (_Float16)(qt[3] * qsc)};
        ka[t] = (f16x4){(_Float16)kt[0], (_Float16)kt[1], (_Float16)kt[2], (_Float16)kt[3]};
        vb[t] = (f16x4){(_Float16)vt[0], (_Float16)vt[1], (_Float16)vt[2], (_Float16)vt[3]};
    }

    // AO base for this lane: row q = qt*16 + lg*4 + r, col c = h*16 + lr.
    unsigned short* aob = AO + ((size_t)(n0 * 128 + w) * 128 + lg * 4) * 128 + h * 16 + lr;

    #pragma unroll
    for (int qt = 0; qt < 8; ++qt) {
        f32x4 s[8];
        #pragma unroll
        for (int kt = 0; kt < 8; ++kt)
            s[kt] = __builtin_amdgcn_mfma_f32_16x16x16f16(ka[kt], qb[qt], zf, 0, 0, 0);
        float sum = 0.f;
        f16x4 pa[8];
        #pragma unroll
        for (int kt = 0; kt < 8; ++kt) {
            float p0 = __builtin_amdgcn_exp2f(s[kt][0]);
            float p1 = __builtin_amdgcn_exp2f(s[kt][1]);
            float p2 = __builtin_amdgcn_exp2f(s[kt][2]);
            float p3 = __builtin_amdgcn_exp2f(s[kt][3]);
            sum += (p0 + p1) + (p2 + p3);
            pa[kt] = (f16x4){(_Float16)p0, (_Float16)p1, (_Float16)p2, (_Float16)p3};
        }
        sum += __shfl_xor(sum, 16);
        sum += __shfl_xor(sum, 32);
        // PV as two independent 4-deep chains (halves serial MFMA latency)
        f32x4 oA = zf, oB = zf;
        #pragma unroll
        for (int kt = 0; kt < 4; ++kt) {
            oA = __builtin_amdgcn_mfma_f32_16x16x16f16(pa[kt],     vb[kt],     oA, 0, 0, 0);
            oB = __builtin_amdgcn_mfma_f32_16x16x16f16(pa[kt + 4], vb[kt + 4], oB, 0, 0, 0);
        }
        f32x4 o = oA + oB;
        float rl = 1.f / sum;      // valid for q-column lr
        #pragma unroll
        for (int r = 0; r < 4; ++r) {
            float rs = __shfl(rl, lg * 4 + r);   // 1/sum for q-row lg*4+r
            aob[((size_t)qt * 16 + r) * 128] = (unsigned short)bf16_rne(o[r] * rs);
        }
    }
}

// MFMA out-proj. Block = (n0, s, w-half); Wo A-frags preloaded to regs,
// AO half-tile staged to LDS; 4 waves, wave wv: e-tile [wv*32,+32) x 64 w.
__global__ __launch_bounds__(256) void axattn_proj(
    const unsigned short* __restrict__ AOb,
    const unsigned short* __restrict__ Wob,
    const float* __restrict__ bo,
    float* __restrict__ out)
{
    int bb  = blockIdx.x;
    int wh  = bb & 1;
    int s   = (bb >> 1) & 127;
    int n0  = bb >> 8;
    int tid = threadIdx.x;
    int wv  = tid >> 6;
    int l   = tid & 63;
    int lr  = l & 15;
    int lg  = l >> 4;
    int lk  = lg * 8;
    int eb  = wv * 32;

    // AO half-tile [w-row 0..63][c 0..127] bf16, row stride 272B (256 + 16 pad)
    __shared__ char as_[64 * 272];

    // A-frags first: global loads overlap the LDS staging below.
    const unsigned short* wp_ = Wob + (size_t)(eb + lr) * 128 + lk;
    bf16x8 a0[4], a1[4];
    #pragma unroll
    for (int ct = 0; ct < 4; ++ct) {
        a0[ct] = *(const bf16x8*)(wp_ + ct * 32);
        a1[ct] = *(const bf16x8*)(wp_ + 16 * 128 + ct * 32);
    }

    #pragma unroll
    for (int it = 0; it < 4; ++it) {
        int flat = it * 256 + tid;     // 0..1023
        int row  = flat >> 4;          // 0..63
        int seg  = flat & 15;
        const uint4* src = (const uint4*)(AOb
            + ((size_t)(n0 * 128 + wh * 64 + row) * 128 + s) * 128) + seg;
        *(uint4*)(as_ + row * 272 + seg * 16) = *src;
    }
    __syncthreads();

    f32x4 acc[2][4];
    #pragma unroll
    for (int mi = 0; mi < 2; ++mi)
        #pragma unroll
        for (int ni = 0; ni < 4; ++ni)
            acc[mi][ni] = (f32x4){0.f, 0.f, 0.f, 0.f};

    #pragma unroll
    for (int ct = 0; ct < 4; ++ct) {             // k = c tile of 32
        #pragma unroll
        for (int ni = 0; ni < 4; ++ni) {
            bf16x8 b = *(const bf16x8*)(as_ + (ni * 16 + lr) * 272 + (lk + ct * 32) * 2);
            acc[0][ni] = __builtin_amdgcn_mfma_f32_16x16x32_bf16(a0[ct], b, acc[0][ni], 0, 0, 0);
            acc[1][ni] = __builtin_amdgcn_mfma_f32_16x16x32_bf16(a1[ct], b, acc[1][ni], 0, 0, 0);
        }
    }

    int r4 = lg * 4;
    #pragma unroll
    for (int mi = 0; mi < 2; ++mi) {
        #pragma unroll
        for (int r = 0; r < 4; ++r) {
            int e = eb + mi * 16 + r4 + r;
            float bv = bo[e];
            float* orow = out + ((size_t)(n0 * 128 + e) * 128 + s) * 128 + wh * 64 + lr;
            #pragma unroll
            for (int ni = 0; ni < 4; ++ni)
                orow[ni * 16] = acc[mi][ni][r] + bv;
        }
    }
}

extern "C" void kernel_launch(void* const* d_in, const int* in_sizes, int n_in,
                              void* d_out, int out_size, void* d_ws, size_t ws_size,
                              hipStream_t stream) {
    const float* x  = (const float*)d_in[0];
    const float* Wq = (const float*)d_in[1];
    const float* Wk = (const float*)d_in[2];
    const float* Wv = (const float*)d_in[3];
    const float* Wo = (const float*)d_in[4];
    const float* bo = (const float*)d_in[5];
    float* out = (float*)d_out;

    unsigned short* AOb = (unsigned short*)d_ws;                        // 32 MiB bf16
    unsigned short* Wob = (unsigned short*)((char*)d_ws + (32u << 20)); // 32 KiB bf16

    axattn_attn<<<512, 1024, 0, stream>>>(x, Wq, Wk, Wv, Wo, Wob, AOb);
    axattn_proj<<<2048, 256, 0, stream>>>(AOb, Wob, bo, out);
}